// Round 9
// baseline (52.878 us; speedup 1.0000x reference)
//
#include <hip/hip_runtime.h>

// QuantGelu: y = pre_x_int * sigmoid_int * (scaler/128)
//   pre_x_int = clip(round(x/scaler), -128, 127)  [per-channel scaler, D=4096]
//   sigmoid via integer shift-exp over {x_int, -row_max}
//
// Round-9: phase-separated block, RPB=4, 2 barriers TOTAL per block:
//   P1: quantize 4 rows (i8-packed pre) + row maxes + x0 range -> barrier
//   P2: fused build of 4 sig tables (ei computed once per entry, no eit
//       table) -> barrier
//   P3: barrier-free lookup + NT-store of all 4 rows.
// Per-channel sentinel fallback (slot byte 255) replaces the block-wide
// slow path. Element math identical to rounds 5-8 -> bit-same output.

#define D 4096
#define BLK 512
#define CPT 8           // BLK*CPT == D
#define RPB 4
#define NW (BLK / 64)
#define NSLOT 9         // x0 slots covered by fast path (data span <= 9)
#define EPS 1e-4f
#define F2_31 2147483648.0f   // fl32(2^31 - 1)

typedef float f32x4 __attribute__((ext_vector_type(4)));

// Exact floor(fl(xi/x0)) for integer-valued xi, integer x0 in [-64,-1],
// clamped ratio in [0,15]: divisible case error << EPS; non-divisible case
// distance to integer >= 1/|x0| >= 1/64 >> EPS. ldexpf = v_ldexp_f32; q<0
// (em path) -> inf, matching np.exp2(15-q)=inf, absorbed by min(esum,2^31).
__device__ __forceinline__ float exp_fast(float xi, float nx0, float rx0) {
    const float q = floorf(fmaf(xi, rx0, EPS));
    const float r = fmaf(nx0, q, xi);      // xi - x0*q, exact (small ints)
    const float e = fmaf(r, 0.5f, nx0);    // r/2 - x0, halves, exact
    return floorf(ldexpf(e, 15 - (int)q)); // e > 0 -> max(.,0) redundant
}

// Fully-IEEE path, exact for any x0 (per-channel sentinel fallback only).
__device__ __forceinline__ float exp_slow(float xi, float x0) {
    xi = fmaxf(xi, 15.0f * x0);
    const float q = floorf(xi / x0);
    const float r = fmaf(-x0, q, xi);
    const float e = fmaf(r, 0.5f, -x0);
    return fmaxf(floorf(e * ldexpf(1.0f, 15 - (int)q)), 0.0f);
}

__global__ __launch_bounds__(BLK) void quantgelu_kernel(
    const float* __restrict__ x, const float* __restrict__ scaler,
    float* __restrict__ out, int nrows)
{
    const int tid  = threadIdx.x;
    const int wid  = tid >> 6;
    const int lane = tid & 63;
    const int row0 = blockIdx.x * RPB;

    __shared__ float sigt[RPB][NSLOT * 256];
    __shared__ __align__(16) float smax[RPB][NW];
    __shared__ __align__(16) float sred[2][NW];

    const int c0 = tid * 4;
    const int c1 = BLK * 4 + tid * 4;

    // row bases (clamped; nrows % RPB == 0 so clamp never fires; stores are
    // validity-guarded so a clamped duplicate load is harmless)
    long long rb[RPB];
    #pragma unroll
    for (int r = 0; r < RPB; ++r)
        rb[r] = (long long)(row0 + r < nrows ? row0 + r : nrows - 1) * D;

    // issue loads for rows 0,1 ASAP
    float4 xv[4];
    xv[0] = *reinterpret_cast<const float4*>(x + rb[0] + c0);
    xv[1] = *reinterpret_cast<const float4*>(x + rb[0] + c1);
    xv[2] = *reinterpret_cast<const float4*>(x + rb[1] + c0);
    xv[3] = *reinterpret_cast<const float4*>(x + rb[1] + c1);

    // ---- per-channel constants ----
    float s_[CPT], rs_[CPT];
    float x0mn, x0mx;
    {
        float mn = 1.0f, mx = -1e30f;
        #pragma unroll
        for (int k = 0; k < 2; ++k) {
            const float4 sv = *reinterpret_cast<const float4*>(scaler + (k ? c1 : c0));
            const float ss[4] = {sv.x, sv.y, sv.z, sv.w};
            #pragma unroll
            for (int j = 0; j < 4; ++j) {
                const int i = k * 4 + j;
                const float s = ss[j];
                s_[i]  = s;
                rs_[i] = 1.0f / s;                          // Markstein seed
                const float x0 = floorf(-1.0f / (s * 1.702f)); // IEEE div
                mn = fminf(mn, x0);
                mx = fmaxf(mx, x0);
            }
        }
        #pragma unroll
        for (int off = 1; off < 64; off <<= 1) {
            mn = fminf(mn, __shfl_xor(mn, off));
            mx = fmaxf(mx, __shfl_xor(mx, off));
        }
        if (lane == 0) { sred[0][wid] = mn; sred[1][wid] = mx; }
        x0mn = mn; x0mx = mx;
    }

    // ---- phase 1: quantize 4 rows, pack pre as i8, publish row maxes ----
    unsigned pk[2 * RPB];
    #pragma unroll
    for (int r = 0; r < RPB; ++r) {
        const int p = (r & 1) * 2;
        float vmax = -INFINITY;
        unsigned pk0 = 0u, pk1 = 0u;
        #pragma unroll
        for (int k = 0; k < 2; ++k) {
            const float* xa = reinterpret_cast<const float*>(&xv[p + k]);
            #pragma unroll
            for (int j = 0; j < 4; ++j) {
                const int i = k * 4 + j;
                const float q0 = xa[j] * rs_[i];
                const float rr = fmaf(-s_[i], q0, xa[j]);
                const float pv = __builtin_amdgcn_fmed3f(
                                    rintf(fmaf(rr, rs_[i], q0)), -128.0f, 127.0f);
                vmax = fmaxf(vmax, pv);
                const unsigned b = ((unsigned)(int)pv & 0xffu) << (8 * j);
                if (k == 0) pk0 |= b; else pk1 |= b;
            }
        }
        pk[2 * r]     = pk0;
        pk[2 * r + 1] = pk1;
        // refill this xv pair with row r+2 (flies across reduce+build)
        if (r + 2 < RPB) {
            xv[p]     = *reinterpret_cast<const float4*>(x + rb[r + 2] + c0);
            xv[p + 1] = *reinterpret_cast<const float4*>(x + rb[r + 2] + c1);
        }
        #pragma unroll
        for (int off = 1; off < 64; off <<= 1)
            vmax = fmaxf(vmax, __shfl_xor(vmax, off));
        if (lane == 0) smax[r][wid] = vmax;
    }

    __syncthreads();            // A: publishes sred (x0 range) + smax (4 rows)

    // ---- x0 window + slot bytes (x0 recomputed; 8 divs/block, negligible) ----
    #pragma unroll
    for (int w = 0; w < NW; ++w) {
        x0mn = fminf(x0mn, sred[0][w]);
        x0mx = fmaxf(x0mx, sred[1][w]);
    }
    const int nsl = (int)(x0mx - x0mn) + 1;
    const int tb  = nsl < NSLOT ? nsl : NSLOT;

    unsigned slotpk[2] = {0u, 0u};
    #pragma unroll
    for (int k = 0; k < 2; ++k)
        #pragma unroll
        for (int j = 0; j < 4; ++j) {
            const float x0 = floorf(-1.0f / (s_[k * 4 + j] * 1.702f));
            const int   sl = (int)(x0 - x0mn);
            const unsigned byte = (x0 >= -64.0f && sl < tb) ? (unsigned)sl : 255u;
            slotpk[k] |= (byte & 0xffu) << (8 * j);
        }

    // ---- row maxes ----
    int   vmaxi[RPB];
    float xmt_[RPB];
    #pragma unroll
    for (int r = 0; r < RPB; ++r) {
        const float4 a = *reinterpret_cast<const float4*>(&smax[r][0]);
        const float4 b = *reinterpret_cast<const float4*>(&smax[r][4]);
        const float vm = fmaxf(fmaxf(fmaxf(a.x, a.y), fmaxf(a.z, a.w)),
                               fmaxf(fmaxf(b.x, b.y), fmaxf(b.z, b.w)));
        vmaxi[r] = (int)vm;
        const float xm = -vm;
        xmt_[r] = xm + floorf(xm * 0.5f) - floorf(xm * 0.0625f);
    }

    // ---- phase 2: fused build of RPB sig tables ----
    {
        const float x0l  = x0mn + (float)lane;  // lane l serves slot l
        const float nx0l = -x0l;
        const float rx0l = 1.0f / x0l;          // IEEE div, 1x per block
        const float c15l = 15.0f * x0l;
        float em_l[RPB];
        #pragma unroll
        for (int r = 0; r < RPB; ++r)
            em_l[r] = exp_fast(fmaxf(xmt_[r], c15l), nx0l, rx0l);

        const int nent = tb << 8;
        for (int e = tid; e < nent; e += BLK) {
            const int   slot = e >> 8;          // wave-uniform (64 | 256)
            const float x0v  = x0mn + (float)slot;
            const float rx0v = __shfl(rx0l, slot);
            float xi = -(float)(e & 255);
            xi = xi + floorf(xi * 0.5f) - floorf(xi * 0.0625f);
            xi = fmaxf(xi, 15.0f * x0v);
            const float ei = exp_fast(xi, -x0v, rx0v);
            #pragma unroll
            for (int r = 0; r < RPB; ++r) {
                const float em = __shfl(em_l[r], slot);
                const float f  = floorf(F2_31 / fminf(ei + em, F2_31)); // IEEE div
                // scaler/128's 2^-7 folded: sig integer <= 128 -> *2^-7 exact
                sigt[r][e] = floorf((ei * f) * 0x1p-24f) * 0.0078125f;
            }
        }
    }
    __syncthreads();            // B: tables ready

    // ---- phase 3: barrier-free lookup + NT store, all rows ----
    #pragma unroll
    for (int r = 0; r < RPB; ++r) {
        if (row0 + r >= nrows) break;           // block-uniform
        #pragma unroll
        for (int k = 0; k < 2; ++k) {
            f32x4 ov;
            #pragma unroll
            for (int j = 0; j < 4; ++j) {
                const int i  = k * 4 + j;
                const int pi = (int)(signed char)((pk[2 * r + k] >> (8 * j)) & 0xffu);
                const unsigned sb = (slotpk[k] >> (8 * j)) & 0xffu;
                if (sb != 255u) {
                    const float sg = sigt[r][((int)sb << 8) + (vmaxi[r] - pi)];
                    ov[j] = ((float)pi * sg) * s_[i];
                } else {
                    // per-channel exact fallback (x0 outside table window)
                    const float x0 = floorf(-1.0f / (s_[i] * 1.702f));
                    const float pf = (float)pi;
                    float xi = pf - (float)vmaxi[r];
                    xi = xi + floorf(xi * 0.5f) - floorf(xi * 0.0625f);
                    const float ei = exp_slow(xi, x0);
                    const float em = exp_slow(xmt_[r], x0);
                    const float factor = floorf(F2_31 / fminf(ei + em, F2_31));
                    ov[j] = (pf * floorf((ei * factor) * 0x1p-24f))
                            * (s_[i] * 0.0078125f);
                }
            }
            __builtin_nontemporal_store(
                ov, reinterpret_cast<f32x4*>(out + rb[r] + (k ? c1 : c0)));
        }
    }
}

extern "C" void kernel_launch(void* const* d_in, const int* in_sizes, int n_in,
                              void* d_out, int out_size, void* d_ws, size_t ws_size,
                              hipStream_t stream) {
    const float* x      = (const float*)d_in[0];
    const float* scaler = (const float*)d_in[1];
    float* out          = (float*)d_out;

    const int nrows = in_sizes[0] / D;                 // 8192
    const int grid  = (nrows + RPB - 1) / RPB;         // 2048
    quantgelu_kernel<<<grid, BLK, 0, stream>>>(x, scaler, out, nrows);
}